// Round 2
// baseline (34047.357 us; speedup 1.0000x reference)
//
#include <hip/hip_runtime.h>
#include <math.h>

#define B 128
#define S 400
#define EENC 512
#define T 300
#define V 30
#define EMB 256
#define H1 512
#define H2 128
#define P 128
#define XD (P + EMB)   // 384 : [context | char_embed]
#define K1 (XD + H1)   // 896 : LSTM1 reduction dim
#define KHALF 448      // K1/2, multiple of 32; region boundaries (128,384) stay chunk-aligned
#define G2 (4 * H2)    // 512
#define PRED_SIZE (B * V * T)

__device__ __forceinline__ float sigmoidf_(float x) { return 1.0f / (1.0f + expf(-x)); }

// bf16 helpers (raw ushort bits; RNE rounding)
__device__ __forceinline__ unsigned short f2bf(float x) {
  unsigned int u = __float_as_uint(x);
  u = (u + 0x7FFFu + ((u >> 16) & 1u)) >> 16;
  return (unsigned short)u;
}
__device__ __forceinline__ float bf2f(unsigned short s) {
  return __uint_as_float(((unsigned int)s) << 16);
}

// ---------------- keys/values precompute GEMM ----------------
// C[m][n], m in [0, B*S), n in [0, 256): n<128 -> keys, else values. Bias folded.
// Outputs stored as bf16 (attention streaming is BW-bound; halves traffic).
__global__ __launch_bounds__(256) void kv_gemm(
    const float* __restrict__ enc, const float* __restrict__ Wk,
    const float* __restrict__ bk, const float* __restrict__ Wv,
    const float* __restrict__ bv, unsigned short* __restrict__ keys,
    unsigned short* __restrict__ values) {
  __shared__ float As[32][68];  // As[k][m], pad 4 keeps float4 aligned
  __shared__ float Ws[32][68];  // Ws[k][n]
  const int tid = threadIdx.x;
  const int m0 = blockIdx.x * 64;
  const int n0 = blockIdx.y * 64;
  const int tm = tid & 15, tn = tid >> 4;
  float acc[4][4] = {};
  for (int kc = 0; kc < EENC; kc += 32) {
    for (int i = tid; i < 64 * 32; i += 256) {
      int mm = i >> 5, kk = i & 31;
      As[kk][mm] = enc[(size_t)(m0 + mm) * EENC + kc + kk];
    }
    for (int i = tid; i < 64 * 32; i += 256) {
      int nn = i >> 5, kk = i & 31;
      int n = n0 + nn;
      Ws[kk][nn] = (n < P) ? Wk[n * EENC + kc + kk] : Wv[(n - P) * EENC + kc + kk];
    }
    __syncthreads();
#pragma unroll
    for (int kk = 0; kk < 32; ++kk) {
      float4 av = *(const float4*)&As[kk][tm * 4];
      float4 wv = *(const float4*)&Ws[kk][tn * 4];
      float a[4] = {av.x, av.y, av.z, av.w};
      float w[4] = {wv.x, wv.y, wv.z, wv.w};
#pragma unroll
      for (int ii = 0; ii < 4; ++ii)
#pragma unroll
        for (int jj = 0; jj < 4; ++jj) acc[ii][jj] += a[ii] * w[jj];
    }
    __syncthreads();
  }
#pragma unroll
  for (int ii = 0; ii < 4; ++ii) {
    int m = m0 + tm * 4 + ii;
#pragma unroll
    for (int jj = 0; jj < 4; ++jj) {
      int n = n0 + tn * 4 + jj;
      if (n < P) keys[(size_t)m * P + n] = f2bf(acc[ii][jj] + bk[n]);
      else       values[(size_t)m * P + (n - P)] = f2bf(acc[ii][jj] + bv[n - P]);
    }
  }
}

// ---------------- context0 = mean over S of values ----------------
__global__ void ctx0_mean(const unsigned short* __restrict__ values,
                          float* __restrict__ context) {
  int b = blockIdx.x, p = threadIdx.x;  // 128 blocks x 128 threads
  float acc = 0.0f;
  for (int s = 0; s < S; ++s) acc += bf2f(values[((size_t)b * S + s) * P + p]);
  context[b * P + p] = acc * (1.0f / (float)S);
}

// ---------------- per-step LSTM1 ----------------
// gates[b][4*H1] = x @ Wih1^T + h1 @ Whh1^T + biases, x = [ctx | emb[tok] | h1_prev]
// 128 blocks x 512 threads. Block nb owns n in {nb*4 .. nb*4+3} (16 gate rows
// across the 4 sections). Threads split K in half (z = tid>>8) for 8 waves/block.
__global__ __launch_bounds__(512) void lstm1_step(
    const float* __restrict__ Wih, const float* __restrict__ Whh,
    const float* __restrict__ bih, const float* __restrict__ bhh,
    const float* __restrict__ emb, const int* __restrict__ y,
    const float* __restrict__ ctx, const float* __restrict__ h1_prev,
    float* __restrict__ h1_new, float* __restrict__ c1, int t) {
  __shared__ float Xl[2][32][B + 4];  // per-K-half X tile, [k][b]
  __shared__ float Wl[2][32][17];     // per-K-half W tile, [k][r]
  __shared__ float Gt[2][16][B + 4];  // partial gate tiles
  __shared__ int tokl[B];
  const int tid = threadIdx.x;
  const int z = tid >> 8;      // K-half
  const int lt = tid & 255;
  const int nb = blockIdx.x;   // 0..127
  const int n0 = nb * 4;
  if (tid < B) tokl[tid] = (t == 0) ? 0 : y[tid * T + t];
  __syncthreads();
  const int tx = lt & 15;      // gate row r in [0,16)
  const int ty = lt >> 4;      // b-group: b0 = ty*8
  float acc[8] = {};
  for (int cc = 0; cc < KHALF / 32; ++cc) {
    const int kc = z * KHALF + cc * 32;
    // ---- stage X tile (float4 along k, transpose into LDS) ----
    if (kc < P) {
      for (int i = lt; i < 8 * B; i += 256) {
        int b = i >> 3, k4 = (i & 7) * 4;
        float4 v = *(const float4*)&ctx[b * P + kc + k4];
        Xl[z][k4 + 0][b] = v.x; Xl[z][k4 + 1][b] = v.y;
        Xl[z][k4 + 2][b] = v.z; Xl[z][k4 + 3][b] = v.w;
      }
    } else if (kc < XD) {
      for (int i = lt; i < 8 * B; i += 256) {
        int b = i >> 3, k4 = (i & 7) * 4;
        float4 v = *(const float4*)&emb[tokl[b] * EMB + (kc - P) + k4];
        Xl[z][k4 + 0][b] = v.x; Xl[z][k4 + 1][b] = v.y;
        Xl[z][k4 + 2][b] = v.z; Xl[z][k4 + 3][b] = v.w;
      }
    } else {
      for (int i = lt; i < 8 * B; i += 256) {
        int b = i >> 3, k4 = (i & 7) * 4;
        float4 v = *(const float4*)&h1_prev[b * H1 + (kc - XD) + k4];
        Xl[z][k4 + 0][b] = v.x; Xl[z][k4 + 1][b] = v.y;
        Xl[z][k4 + 2][b] = v.z; Xl[z][k4 + 3][b] = v.w;
      }
    }
    // ---- stage W tile (16 rows x 32 k) ----
    if (kc < XD) {
      for (int i = lt; i < 128; i += 256) {
        int r = i >> 3, kq = (i & 7) * 4;
        int rr = (r >> 2) * H1 + n0 + (r & 3);
        float4 v = *(const float4*)&Wih[rr * XD + kc + kq];
        Wl[z][kq + 0][r] = v.x; Wl[z][kq + 1][r] = v.y;
        Wl[z][kq + 2][r] = v.z; Wl[z][kq + 3][r] = v.w;
      }
    } else {
      for (int i = lt; i < 128; i += 256) {
        int r = i >> 3, kq = (i & 7) * 4;
        int rr = (r >> 2) * H1 + n0 + (r & 3);
        float4 v = *(const float4*)&Whh[rr * H1 + (kc - XD) + kq];
        Wl[z][kq + 0][r] = v.x; Wl[z][kq + 1][r] = v.y;
        Wl[z][kq + 2][r] = v.z; Wl[z][kq + 3][r] = v.w;
      }
    }
    __syncthreads();
#pragma unroll
    for (int kk = 0; kk < 32; ++kk) {
      float w = Wl[z][kk][tx];
      float4 xa = *(const float4*)&Xl[z][kk][ty * 8];
      float4 xb = *(const float4*)&Xl[z][kk][ty * 8 + 4];
      acc[0] += w * xa.x; acc[1] += w * xa.y; acc[2] += w * xa.z; acc[3] += w * xa.w;
      acc[4] += w * xb.x; acc[5] += w * xb.y; acc[6] += w * xb.z; acc[7] += w * xb.w;
    }
    __syncthreads();
  }
  {
    float4 v0 = {acc[0], acc[1], acc[2], acc[3]};
    float4 v1 = {acc[4], acc[5], acc[6], acc[7]};
    *(float4*)&Gt[z][tx][ty * 8] = v0;
    *(float4*)&Gt[z][tx][ty * 8 + 4] = v1;
  }
  __syncthreads();
  // epilogue: 4 n x 128 b outputs, exactly one per thread. sections i,f,g,o
  {
    int j = tid >> 7, b = tid & 127;
    int n = n0 + j;
    float gi = Gt[0][0 * 4 + j][b] + Gt[1][0 * 4 + j][b] + bih[n] + bhh[n];
    float gf = Gt[0][1 * 4 + j][b] + Gt[1][1 * 4 + j][b] + bih[H1 + n] + bhh[H1 + n];
    float gg = Gt[0][2 * 4 + j][b] + Gt[1][2 * 4 + j][b] + bih[2 * H1 + n] + bhh[2 * H1 + n];
    float go = Gt[0][3 * 4 + j][b] + Gt[1][3 * 4 + j][b] + bih[3 * H1 + n] + bhh[3 * H1 + n];
    float ii = sigmoidf_(gi), ff = sigmoidf_(gf), tg = tanhf(gg), oo = sigmoidf_(go);
    float cold = c1[b * H1 + n];
    float cn = ff * cold + ii * tg;
    c1[b * H1 + n] = cn;
    h1_new[b * H1 + n] = oo * tanhf(cn);
  }
}

// ---------------- per-step: LSTM2 + q + attention + logits ----------------
// 64 blocks x 512 threads; each block owns 2 batch rows (shares W reads).
__global__ __launch_bounds__(512) void step_rest(
    const float* __restrict__ Wih2, const float* __restrict__ Whh2,
    const float* __restrict__ bih2, const float* __restrict__ bhh2,
    const float* __restrict__ Wq, const float* __restrict__ bq,
    const float* __restrict__ emb, const float* __restrict__ b_out,
    const int* __restrict__ lens, const unsigned short* __restrict__ keys,
    const unsigned short* __restrict__ values, const float* __restrict__ h1,
    float* __restrict__ h2, float* __restrict__ c2,
    float* __restrict__ context, float* __restrict__ out, int t) {
  __shared__ float hl[2][H1];
  __shared__ float h2l[2][H2];
  __shared__ float g2[2][G2];
  __shared__ float ql[2][P];
  __shared__ float ctxp[2][2][P];
  __shared__ float sc[2][S];
  __shared__ float red[2][256];
  const int tid = threadIdx.x;
  const int b0 = blockIdx.x * 2;
  for (int i = tid; i < 2 * H1; i += 512) hl[i >> 9][i & 511] = h1[(b0 + (i >> 9)) * H1 + (i & 511)];
  if (tid < 2 * H2) h2l[tid >> 7][tid & 127] = h2[(b0 + (tid >> 7)) * H2 + (tid & 127)];
  __syncthreads();
  // gates2: 512 rows, one per thread, both b
  {
    int r = tid;
    float a0 = bih2[r] + bhh2[r];
    float a1 = a0;
    const float* wr = &Wih2[r * H1];
#pragma unroll 4
    for (int k = 0; k < H1; k += 4) {
      float4 w = *(const float4*)&wr[k];
      a0 += w.x * hl[0][k] + w.y * hl[0][k + 1] + w.z * hl[0][k + 2] + w.w * hl[0][k + 3];
      a1 += w.x * hl[1][k] + w.y * hl[1][k + 1] + w.z * hl[1][k + 2] + w.w * hl[1][k + 3];
    }
    const float* wr2 = &Whh2[r * H2];
#pragma unroll 4
    for (int k = 0; k < H2; k += 4) {
      float4 w = *(const float4*)&wr2[k];
      a0 += w.x * h2l[0][k] + w.y * h2l[0][k + 1] + w.z * h2l[0][k + 2] + w.w * h2l[0][k + 3];
      a1 += w.x * h2l[1][k] + w.y * h2l[1][k + 1] + w.z * h2l[1][k + 2] + w.w * h2l[1][k + 3];
    }
    g2[0][r] = a0;
    g2[1][r] = a1;
  }
  __syncthreads();
  // h2/c2 update (gate order i,f,g,o in chunks of 128)
  if (tid < 256) {
    int bb = tid >> 7, n = tid & 127;
    int b = b0 + bb;
    float ii = sigmoidf_(g2[bb][n]);
    float ff = sigmoidf_(g2[bb][H2 + n]);
    float tg = tanhf(g2[bb][2 * H2 + n]);
    float oo = sigmoidf_(g2[bb][3 * H2 + n]);
    float cn = ff * c2[b * H2 + n] + ii * tg;
    float hn = oo * tanhf(cn);
    c2[b * H2 + n] = cn;
    h2[b * H2 + n] = hn;
    h2l[bb][n] = hn;
  }
  __syncthreads();
  // q = h2_new @ Wq^T + bq
  if (tid < 256) {
    int bb = tid >> 7, p = tid & 127;
    float a = bq[p];
    const float* wr = &Wq[p * H2];
#pragma unroll 4
    for (int k = 0; k < H2; k += 4) {
      float4 w = *(const float4*)&wr[k];
      a += w.x * h2l[bb][k] + w.y * h2l[bb][k + 1] + w.z * h2l[bb][k + 2] + w.w * h2l[bb][k + 3];
    }
    ql[bb][p] = a;
  }
  __syncthreads();
  // masked scaled scores (keys are bf16, 8 elems per 16B load)
  const float scale = 0.08838834764831845f;  // 1/sqrt(128)
  for (int i = tid; i < 2 * S; i += 512) {
    int bb = (i < S) ? 0 : 1;
    int s = i - bb * S;
    int b = b0 + bb;
    const uint4* kr = (const uint4*)&keys[((size_t)b * S + s) * P];
    float a = 0.0f;
#pragma unroll
    for (int k8 = 0; k8 < 16; ++k8) {
      uint4 u = kr[k8];
      const float* q8 = &ql[bb][k8 * 8];
      a += __uint_as_float(u.x << 16) * q8[0] + __uint_as_float(u.x & 0xffff0000u) * q8[1];
      a += __uint_as_float(u.y << 16) * q8[2] + __uint_as_float(u.y & 0xffff0000u) * q8[3];
      a += __uint_as_float(u.z << 16) * q8[4] + __uint_as_float(u.z & 0xffff0000u) * q8[5];
      a += __uint_as_float(u.w << 16) * q8[6] + __uint_as_float(u.w & 0xffff0000u) * q8[7];
    }
    a *= scale;
    if (s >= lens[b]) a = -1e9f;
    sc[bb][s] = a;
  }
  __syncthreads();
  // softmax over S per row (2 rows x 256 threads)
  const int bb = tid >> 8, sl = tid & 255;
  float m = -INFINITY;
  for (int s = sl; s < S; s += 256) m = fmaxf(m, sc[bb][s]);
  red[bb][sl] = m;
  __syncthreads();
  for (int off = 128; off > 0; off >>= 1) {
    if (sl < off) red[bb][sl] = fmaxf(red[bb][sl], red[bb][sl + off]);
    __syncthreads();
  }
  float mx = red[bb][0];
  __syncthreads();
  float ssum = 0.0f;
  for (int s = sl; s < S; s += 256) {
    float e = expf(sc[bb][s] - mx);
    sc[bb][s] = e;
    ssum += e;
  }
  red[bb][sl] = ssum;
  __syncthreads();
  for (int off = 128; off > 0; off >>= 1) {
    if (sl < off) red[bb][sl] += red[bb][sl + off];
    __syncthreads();
  }
  float inv = 1.0f / red[bb][0];
  for (int s = sl; s < S; s += 256) {
    float w = sc[bb][s] * inv;
    sc[bb][s] = w;
    if (b0 + bb == 0) out[PRED_SIZE + (size_t)t * S + s] = w;  // attention_plot row
  }
  __syncthreads();
  // context = w @ values (S split in half across thread pairs)
  {
    int cbb = tid >> 8, sh = (tid >> 7) & 1, ph = tid & 127;
    int b = b0 + cbb;
    float a = 0.0f;
    for (int s = sh * 200; s < sh * 200 + 200; ++s)
      a += sc[cbb][s] * bf2f(values[((size_t)b * S + s) * P + ph]);
    ctxp[cbb][sh][ph] = a;
  }
  __syncthreads();
  {
    int cbb = tid >> 8, sh = (tid >> 7) & 1, ph = tid & 127;
    if (sh == 0) {
      float c = ctxp[cbb][0][ph] + ctxp[cbb][1][ph];
      context[(b0 + cbb) * P + ph] = c;
      ctxp[cbb][0][ph] = c;
    }
  }
  __syncthreads();
  // logits = [context | h2] @ emb^T + b_out -> predictions[b][v][t]
  // 8 lanes per (bb,v) pair, k split 8 x 32, shuffle-reduce
  {
    int g = tid >> 3, l3 = tid & 7;
    if (g < 2 * V) {
      int gbb = g / V, v = g - gbb * V;
      float a = 0.0f;
      const float* er = &emb[v * EMB + l3 * 32];
#pragma unroll
      for (int k = 0; k < 32; ++k) {
        int kk = l3 * 32 + k;
        float xv = (kk < P) ? ctxp[gbb][0][kk] : h2l[gbb][kk - P];
        a += er[k] * xv;
      }
      a += __shfl_down(a, 4, 8);
      a += __shfl_down(a, 2, 8);
      a += __shfl_down(a, 1, 8);
      if (l3 == 0) out[((size_t)(b0 + gbb) * V + v) * T + t] = a + b_out[v];
    }
  }
}

extern "C" void kernel_launch(void* const* d_in, const int* in_sizes, int n_in,
                              void* d_out, int out_size, void* d_ws, size_t ws_size,
                              hipStream_t stream) {
  const float* enc  = (const float*)d_in[0];
  const int*   lens = (const int*)d_in[1];
  const int*   y    = (const int*)d_in[2];
  const float* emb  = (const float*)d_in[3];
  const float* Wih1 = (const float*)d_in[4];
  const float* Whh1 = (const float*)d_in[5];
  const float* bih1 = (const float*)d_in[6];
  const float* bhh1 = (const float*)d_in[7];
  const float* Wih2 = (const float*)d_in[8];
  const float* Whh2 = (const float*)d_in[9];
  const float* bih2 = (const float*)d_in[10];
  const float* bhh2 = (const float*)d_in[11];
  const float* Wk   = (const float*)d_in[12];
  const float* bk   = (const float*)d_in[13];
  const float* Wv   = (const float*)d_in[14];
  const float* bv   = (const float*)d_in[15];
  const float* Wq   = (const float*)d_in[16];
  const float* bq   = (const float*)d_in[17];
  const float* b_out= (const float*)d_in[18];
  float* out = (float*)d_out;

  float* ws_f = (float*)d_ws;
  float* h1a  = ws_f;                 // B*H1
  float* h1b  = h1a + B * H1;
  float* c1   = h1b + B * H1;
  float* h2   = c1 + B * H1;
  float* c2   = h2 + B * H2;
  float* ctx  = c2 + B * H2;          // B*P
  unsigned short* keys_bf   = (unsigned short*)(ctx + B * P);
  unsigned short* values_bf = keys_bf + (size_t)B * S * P;

  // zero h1a,h1b,c1,h2,c2 (contiguous)
  hipMemsetAsync(h1a, 0, (size_t)(3 * B * H1 + 2 * B * H2) * sizeof(float), stream);

  kv_gemm<<<dim3((B * S) / 64, 4), 256, 0, stream>>>(enc, Wk, bk, Wv, bv, keys_bf, values_bf);
  ctx0_mean<<<B, P, 0, stream>>>(values_bf, ctx);

  for (int t = 0; t < T; ++t) {
    const float* h1_prev = (t & 1) ? h1b : h1a;
    float* h1_new = (t & 1) ? h1a : h1b;
    lstm1_step<<<128, 512, 0, stream>>>(Wih1, Whh1, bih1, bhh1, emb, y, ctx,
                                        h1_prev, h1_new, c1, t);
    step_rest<<<64, 512, 0, stream>>>(Wih2, Whh2, bih2, bhh2, Wq, bq, emb, b_out,
                                      lens, keys_bf, values_bf, h1_new, h2, c2, ctx, out, t);
  }
}

// Round 3
// 15103.494 us; speedup vs baseline: 2.2543x; 2.2543x over previous
//
#include <hip/hip_runtime.h>
#include <math.h>

#define B 128
#define S 400
#define EENC 512
#define T 300
#define V 30
#define EMB 256
#define H1 512
#define H2 128
#define P 128
#define XD (P + EMB)   // 384 : [context | char_embed]
#define K1 (XD + H1)   // 896 : LSTM1 reduction dim
#define K2 (H1 + H2)   // 640 : LSTM2 reduction dim
#define N1 (4 * H1)    // 2048
#define N2 (4 * H2)    // 512
#define PRED_SIZE (B * V * T)

typedef __attribute__((ext_vector_type(8))) short short8v;
typedef __attribute__((ext_vector_type(4))) float f32x4;

__device__ __forceinline__ float sigmoidf_(float x) { return 1.0f / (1.0f + expf(-x)); }

// bf16 helpers (raw ushort bits; RNE rounding)
__device__ __forceinline__ unsigned short f2bf(float x) {
  unsigned int u = __float_as_uint(x);
  u = (u + 0x7FFFu + ((u >> 16) & 1u)) >> 16;
  return (unsigned short)u;
}
__device__ __forceinline__ float bf2f(unsigned short s) {
  return __uint_as_float(((unsigned int)s) << 16);
}

// ---------------- one-time weight prep ----------------
// W1r[n'][k], n' = 4*h + s (s = gate section i,f,g,o), k = [Wih1 cols | Whh1 cols]
// W2r[n'][k] likewise. Split each f32 into bf16 hi + bf16 lo (residual).
__global__ void prep_weights(
    const float* __restrict__ Wih1, const float* __restrict__ Whh1,
    const float* __restrict__ bih1, const float* __restrict__ bhh1,
    const float* __restrict__ Wih2, const float* __restrict__ Whh2,
    const float* __restrict__ bih2, const float* __restrict__ bhh2,
    unsigned short* __restrict__ W1h, unsigned short* __restrict__ W1l,
    unsigned short* __restrict__ W2h, unsigned short* __restrict__ W2l,
    float* __restrict__ b1r, float* __restrict__ b2r) {
  const int T1 = N1 * K1;          // 1,835,008
  const int T2 = N2 * K2;          // 327,680
  const int TOT = T1 + T2 + N1 + N2;
  for (int idx = blockIdx.x * blockDim.x + threadIdx.x; idx < TOT;
       idx += gridDim.x * blockDim.x) {
    if (idx < T1) {
      int np = idx / K1, k = idx - np * K1;
      int h = np >> 2, s = np & 3;
      int no = s * H1 + h;
      float v = (k < XD) ? Wih1[no * XD + k] : Whh1[no * H1 + (k - XD)];
      unsigned short hb = f2bf(v);
      W1h[idx] = hb;
      W1l[idx] = f2bf(v - bf2f(hb));
    } else if (idx < T1 + T2) {
      int i2 = idx - T1;
      int np = i2 / K2, k = i2 - np * K2;
      int h = np >> 2, s = np & 3;
      int no = s * H2 + h;
      float v = (k < H1) ? Wih2[no * H1 + k] : Whh2[no * H2 + (k - H1)];
      unsigned short hb = f2bf(v);
      W2h[i2] = hb;
      W2l[i2] = f2bf(v - bf2f(hb));
    } else if (idx < T1 + T2 + N1) {
      int np = idx - T1 - T2;
      int h = np >> 2, s = np & 3;
      int no = s * H1 + h;
      b1r[np] = bih1[no] + bhh1[no];
    } else {
      int np = idx - T1 - T2 - N1;
      int h = np >> 2, s = np & 3;
      int no = s * H2 + h;
      b2r[np] = bih2[no] + bhh2[no];
    }
  }
}

// ---------------- keys/values precompute GEMM (bf16 out) ----------------
__global__ __launch_bounds__(256) void kv_gemm(
    const float* __restrict__ enc, const float* __restrict__ Wk,
    const float* __restrict__ bk, const float* __restrict__ Wv,
    const float* __restrict__ bv, unsigned short* __restrict__ keys,
    unsigned short* __restrict__ values) {
  __shared__ float As[32][68];
  __shared__ float Ws[32][68];
  const int tid = threadIdx.x;
  const int m0 = blockIdx.x * 64;
  const int n0 = blockIdx.y * 64;
  const int tm = tid & 15, tn = tid >> 4;
  float acc[4][4] = {};
  for (int kc = 0; kc < EENC; kc += 32) {
    for (int i = tid; i < 64 * 32; i += 256) {
      int mm = i >> 5, kk = i & 31;
      As[kk][mm] = enc[(size_t)(m0 + mm) * EENC + kc + kk];
    }
    for (int i = tid; i < 64 * 32; i += 256) {
      int nn = i >> 5, kk = i & 31;
      int n = n0 + nn;
      Ws[kk][nn] = (n < P) ? Wk[n * EENC + kc + kk] : Wv[(n - P) * EENC + kc + kk];
    }
    __syncthreads();
#pragma unroll
    for (int kk = 0; kk < 32; ++kk) {
      float4 av = *(const float4*)&As[kk][tm * 4];
      float4 wv = *(const float4*)&Ws[kk][tn * 4];
      float a[4] = {av.x, av.y, av.z, av.w};
      float w[4] = {wv.x, wv.y, wv.z, wv.w};
#pragma unroll
      for (int ii = 0; ii < 4; ++ii)
#pragma unroll
        for (int jj = 0; jj < 4; ++jj) acc[ii][jj] += a[ii] * w[jj];
    }
    __syncthreads();
  }
#pragma unroll
  for (int ii = 0; ii < 4; ++ii) {
    int m = m0 + tm * 4 + ii;
#pragma unroll
    for (int jj = 0; jj < 4; ++jj) {
      int n = n0 + tn * 4 + jj;
      if (n < P) keys[(size_t)m * P + n] = f2bf(acc[ii][jj] + bk[n]);
      else       values[(size_t)m * P + (n - P)] = f2bf(acc[ii][jj] + bv[n - P]);
    }
  }
}

// ---------------- context0 = mean over S of values (split-bf16 out) ----------------
__global__ void ctx0_mean(const unsigned short* __restrict__ values,
                          unsigned short* __restrict__ ch,
                          unsigned short* __restrict__ cl) {
  int b = blockIdx.x, p = threadIdx.x;
  float acc = 0.0f;
  for (int s = 0; s < S; ++s) acc += bf2f(values[((size_t)b * S + s) * P + p]);
  float m = acc * (1.0f / (float)S);
  unsigned short hb = f2bf(m);
  ch[b * P + p] = hb;
  cl[b * P + p] = f2bf(m - bf2f(hb));
}

// ---------------- LSTM1 step: split-bf16 MFMA GEMM + fused cell update ----------------
// Gate GEMM: G[b][n'] = X[b][:] . W1r[n'][:], X = [ctx | emb[tok] | h1_prev].
// Grid (N1/16=128, B/64=2), 256 threads = 4 waves; wave w owns rows m0+16w..+15, cols n0..n0+15.
__global__ __launch_bounds__(256) void lstm1_mfma(
    const unsigned short* __restrict__ W1h, const unsigned short* __restrict__ W1l,
    const float* __restrict__ b1r, const float* __restrict__ emb,
    const int* __restrict__ y,
    const unsigned short* __restrict__ ctxh, const unsigned short* __restrict__ ctxlo,
    const unsigned short* __restrict__ h1ph, const unsigned short* __restrict__ h1pl,
    unsigned short* __restrict__ h1nh, unsigned short* __restrict__ h1nl,
    float* __restrict__ c1, int t) {
  __shared__ float Gt[64][20];
  const int tid = threadIdx.x;
  const int w = tid >> 6, l = tid & 63;
  const int lr = l & 15, lq = l >> 4;
  const int n0 = blockIdx.x * 16;
  const int m0 = blockIdx.y * 64;
  const int brow = m0 + w * 16 + lr;           // batch row for A
  const int nrow = n0 + lr;                    // gate col for B
  const int tok = (t == 0) ? 0 : y[brow * T + t];
  const unsigned short* wph = W1h + (size_t)nrow * K1;
  const unsigned short* wpl = W1l + (size_t)nrow * K1;
  f32x4 acc = {0.f, 0.f, 0.f, 0.f};
  for (int kc = 0; kc < K1; kc += 32) {
    const int ko = kc + lq * 8;
    short8v ah, al;
    if (kc < P) {
      ah = *(const short8v*)(ctxh + brow * P + ko);
      al = *(const short8v*)(ctxlo + brow * P + ko);
    } else if (kc < XD) {
      const float* ep = emb + tok * EMB + (ko - P);
      float4 e0 = *(const float4*)ep;
      float4 e1 = *(const float4*)(ep + 4);
      float ev[8] = {e0.x, e0.y, e0.z, e0.w, e1.x, e1.y, e1.z, e1.w};
#pragma unroll
      for (int j = 0; j < 8; ++j) {
        unsigned short hs = f2bf(ev[j]);
        ah[j] = (short)hs;
        al[j] = (short)f2bf(ev[j] - bf2f(hs));
      }
    } else {
      ah = *(const short8v*)(h1ph + brow * H1 + (ko - XD));
      al = *(const short8v*)(h1pl + brow * H1 + (ko - XD));
    }
    short8v bh = *(const short8v*)(wph + ko);
    short8v bl = *(const short8v*)(wpl + ko);
    acc = __builtin_amdgcn_mfma_f32_16x16x32_bf16(ah, bh, acc, 0, 0, 0);
    acc = __builtin_amdgcn_mfma_f32_16x16x32_bf16(ah, bl, acc, 0, 0, 0);
    acc = __builtin_amdgcn_mfma_f32_16x16x32_bf16(al, bh, acc, 0, 0, 0);
  }
  // D[row][col]: row = 4*lq + r (within wave tile), col = lr
#pragma unroll
  for (int r = 0; r < 4; ++r) Gt[w * 16 + lq * 4 + r][lr] = acc[r];
  __syncthreads();
  // fused cell update: thread -> (b_local = tid&63, h_local = tid>>6)
  const int bl_ = tid & 63, hl = tid >> 6;
  const int b = m0 + bl_;
  const int hg = blockIdx.x * 4 + hl;          // hidden index in [0,512)
  float gi = Gt[bl_][4 * hl + 0] + b1r[n0 + 4 * hl + 0];
  float gf = Gt[bl_][4 * hl + 1] + b1r[n0 + 4 * hl + 1];
  float gg = Gt[bl_][4 * hl + 2] + b1r[n0 + 4 * hl + 2];
  float go = Gt[bl_][4 * hl + 3] + b1r[n0 + 4 * hl + 3];
  float ii = sigmoidf_(gi), ff = sigmoidf_(gf), tg = tanhf(gg), oo = sigmoidf_(go);
  float cn = ff * c1[b * H1 + hg] + ii * tg;
  c1[b * H1 + hg] = cn;
  float hn = oo * tanhf(cn);
  unsigned short hb = f2bf(hn);
  h1nh[b * H1 + hg] = hb;
  h1nl[b * H1 + hg] = f2bf(hn - bf2f(hb));
}

// ---------------- LSTM2 step: same template, K=640, N=512 ----------------
// Grid (N2/16=32, B/64=2).
__global__ __launch_bounds__(256) void lstm2_mfma(
    const unsigned short* __restrict__ W2h, const unsigned short* __restrict__ W2l,
    const float* __restrict__ b2r,
    const unsigned short* __restrict__ h1ch, const unsigned short* __restrict__ h1cl,
    const unsigned short* __restrict__ h2ph, const unsigned short* __restrict__ h2pl,
    unsigned short* __restrict__ h2nh, unsigned short* __restrict__ h2nl,
    float* __restrict__ c2) {
  __shared__ float Gt[64][20];
  const int tid = threadIdx.x;
  const int w = tid >> 6, l = tid & 63;
  const int lr = l & 15, lq = l >> 4;
  const int n0 = blockIdx.x * 16;
  const int m0 = blockIdx.y * 64;
  const int brow = m0 + w * 16 + lr;
  const int nrow = n0 + lr;
  const unsigned short* wph = W2h + (size_t)nrow * K2;
  const unsigned short* wpl = W2l + (size_t)nrow * K2;
  f32x4 acc = {0.f, 0.f, 0.f, 0.f};
  for (int kc = 0; kc < K2; kc += 32) {
    const int ko = kc + lq * 8;
    short8v ah, al;
    if (kc < H1) {
      ah = *(const short8v*)(h1ch + brow * H1 + ko);
      al = *(const short8v*)(h1cl + brow * H1 + ko);
    } else {
      ah = *(const short8v*)(h2ph + brow * H2 + (ko - H1));
      al = *(const short8v*)(h2pl + brow * H2 + (ko - H1));
    }
    short8v bh = *(const short8v*)(wph + ko);
    short8v bl = *(const short8v*)(wpl + ko);
    acc = __builtin_amdgcn_mfma_f32_16x16x32_bf16(ah, bh, acc, 0, 0, 0);
    acc = __builtin_amdgcn_mfma_f32_16x16x32_bf16(ah, bl, acc, 0, 0, 0);
    acc = __builtin_amdgcn_mfma_f32_16x16x32_bf16(al, bh, acc, 0, 0, 0);
  }
#pragma unroll
  for (int r = 0; r < 4; ++r) Gt[w * 16 + lq * 4 + r][lr] = acc[r];
  __syncthreads();
  const int bl_ = tid & 63, hl = tid >> 6;
  const int b = m0 + bl_;
  const int hg = blockIdx.x * 4 + hl;          // hidden index in [0,128)
  float gi = Gt[bl_][4 * hl + 0] + b2r[n0 + 4 * hl + 0];
  float gf = Gt[bl_][4 * hl + 1] + b2r[n0 + 4 * hl + 1];
  float gg = Gt[bl_][4 * hl + 2] + b2r[n0 + 4 * hl + 2];
  float go = Gt[bl_][4 * hl + 3] + b2r[n0 + 4 * hl + 3];
  float ii = sigmoidf_(gi), ff = sigmoidf_(gf), tg = tanhf(gg), oo = sigmoidf_(go);
  float cn = ff * c2[b * H2 + hg] + ii * tg;
  c2[b * H2 + hg] = cn;
  float hn = oo * tanhf(cn);
  unsigned short hb = f2bf(hn);
  h2nh[b * H2 + hg] = hb;
  h2nl[b * H2 + hg] = f2bf(hn - bf2f(hb));
}

// ---------------- attention + logits: one block per batch row ----------------
__global__ __launch_bounds__(256) void attn_step(
    const float* __restrict__ Wq, const float* __restrict__ bq,
    const float* __restrict__ emb, const float* __restrict__ b_out,
    const int* __restrict__ lens, const unsigned short* __restrict__ keys,
    const unsigned short* __restrict__ values,
    const unsigned short* __restrict__ h2h, const unsigned short* __restrict__ h2lo,
    unsigned short* __restrict__ ctxh, unsigned short* __restrict__ ctxlo,
    float* __restrict__ out, int t) {
  __shared__ float h2f[H2];
  __shared__ float qv[P];
  __shared__ float sc[S];
  __shared__ float red[256];
  __shared__ float cpart[2][P];
  __shared__ float ctxf[P];
  const int tid = threadIdx.x;
  const int b = blockIdx.x;
  if (tid < H2) h2f[tid] = bf2f(h2h[b * H2 + tid]) + bf2f(h2lo[b * H2 + tid]);
  __syncthreads();
  // q = h2 @ Wq^T + bq
  if (tid < P) {
    float a = bq[tid];
    const float* wr = &Wq[tid * H2];
#pragma unroll 4
    for (int k = 0; k < H2; k += 4) {
      float4 wv = *(const float4*)&wr[k];
      a += wv.x * h2f[k] + wv.y * h2f[k + 1] + wv.z * h2f[k + 2] + wv.w * h2f[k + 3];
    }
    qv[tid] = a;
  }
  __syncthreads();
  // masked scaled scores
  const float scale = 0.08838834764831845f;  // 1/sqrt(128)
  const int len = lens[b];
  for (int s = tid; s < S; s += 256) {
    const uint4* kr = (const uint4*)&keys[((size_t)b * S + s) * P];
    float a = 0.0f;
#pragma unroll
    for (int k8 = 0; k8 < 16; ++k8) {
      uint4 u = kr[k8];
      const float* q8 = &qv[k8 * 8];
      a += __uint_as_float(u.x << 16) * q8[0] + __uint_as_float(u.x & 0xffff0000u) * q8[1];
      a += __uint_as_float(u.y << 16) * q8[2] + __uint_as_float(u.y & 0xffff0000u) * q8[3];
      a += __uint_as_float(u.z << 16) * q8[4] + __uint_as_float(u.z & 0xffff0000u) * q8[5];
      a += __uint_as_float(u.w << 16) * q8[6] + __uint_as_float(u.w & 0xffff0000u) * q8[7];
    }
    a *= scale;
    if (s >= len) a = -1e9f;
    sc[s] = a;
  }
  __syncthreads();
  // softmax over S
  float m = -INFINITY;
  for (int s = tid; s < S; s += 256) m = fmaxf(m, sc[s]);
  red[tid] = m;
  __syncthreads();
  for (int off = 128; off > 0; off >>= 1) {
    if (tid < off) red[tid] = fmaxf(red[tid], red[tid + off]);
    __syncthreads();
  }
  const float mx = red[0];
  __syncthreads();
  float ssum = 0.0f;
  for (int s = tid; s < S; s += 256) {
    float e = expf(sc[s] - mx);
    sc[s] = e;
    ssum += e;
  }
  red[tid] = ssum;
  __syncthreads();
  for (int off = 128; off > 0; off >>= 1) {
    if (tid < off) red[tid] += red[tid + off];
    __syncthreads();
  }
  const float inv = 1.0f / red[0];
  for (int s = tid; s < S; s += 256) {
    float wv = sc[s] * inv;
    sc[s] = wv;
    if (b == 0) out[PRED_SIZE + (size_t)t * S + s] = wv;  // attention_plot row
  }
  __syncthreads();
  // context = w @ values (S halved across thread groups)
  {
    const int g = tid >> 7, p = tid & 127;
    float a = 0.0f;
    for (int s = g * 200; s < g * 200 + 200; ++s)
      a += sc[s] * bf2f(values[((size_t)b * S + s) * P + p]);
    cpart[g][p] = a;
  }
  __syncthreads();
  if (tid < P) {
    float c = cpart[0][tid] + cpart[1][tid];
    ctxf[tid] = c;
    unsigned short hb = f2bf(c);
    ctxh[b * P + tid] = hb;
    ctxlo[b * P + tid] = f2bf(c - bf2f(hb));
  }
  __syncthreads();
  // logits = [context | h2] @ emb^T + b_out -> predictions[b][v][t]
  {
    const int g3 = tid >> 3, l3 = tid & 7;
    if (g3 < V) {
      float a = 0.0f;
      const float* er = &emb[g3 * EMB + l3 * 32];
#pragma unroll
      for (int k = 0; k < 32; ++k) {
        int kk = l3 * 32 + k;
        float xv = (kk < P) ? ctxf[kk] : h2f[kk - P];
        a += er[k] * xv;
      }
      a += __shfl_down(a, 4, 8);
      a += __shfl_down(a, 2, 8);
      a += __shfl_down(a, 1, 8);
      if (l3 == 0) out[((size_t)b * V + g3) * T + t] = a + b_out[g3];
    }
  }
}

extern "C" void kernel_launch(void* const* d_in, const int* in_sizes, int n_in,
                              void* d_out, int out_size, void* d_ws, size_t ws_size,
                              hipStream_t stream) {
  const float* enc  = (const float*)d_in[0];
  const int*   lens = (const int*)d_in[1];
  const int*   y    = (const int*)d_in[2];
  const float* emb  = (const float*)d_in[3];
  const float* Wih1 = (const float*)d_in[4];
  const float* Whh1 = (const float*)d_in[5];
  const float* bih1 = (const float*)d_in[6];
  const float* bhh1 = (const float*)d_in[7];
  const float* Wih2 = (const float*)d_in[8];
  const float* Whh2 = (const float*)d_in[9];
  const float* bih2 = (const float*)d_in[10];
  const float* bhh2 = (const float*)d_in[11];
  const float* Wk   = (const float*)d_in[12];
  const float* bk   = (const float*)d_in[13];
  const float* Wv   = (const float*)d_in[14];
  const float* bv   = (const float*)d_in[15];
  const float* Wq   = (const float*)d_in[16];
  const float* bq   = (const float*)d_in[17];
  const float* b_out= (const float*)d_in[18];
  float* out = (float*)d_out;

  // ---- workspace layout (zeroed region first, then the rest) ----
  char* cur = (char*)d_ws;
  float* c1 = (float*)cur;                 cur += (size_t)B * H1 * 4;    // 256 KB
  float* c2 = (float*)cur;                 cur += (size_t)B * H2 * 4;    // 64 KB
  unsigned short* h1a_h = (unsigned short*)cur; cur += (size_t)B * H1 * 2;
  unsigned short* h1a_l = (unsigned short*)cur; cur += (size_t)B * H1 * 2;
  unsigned short* h2a_h = (unsigned short*)cur; cur += (size_t)B * H2 * 2;
  unsigned short* h2a_l = (unsigned short*)cur; cur += (size_t)B * H2 * 2;
  const size_t zero_bytes = (size_t)cur - (size_t)d_ws;  // 655,360 B
  unsigned short* h1b_h = (unsigned short*)cur; cur += (size_t)B * H1 * 2;
  unsigned short* h1b_l = (unsigned short*)cur; cur += (size_t)B * H1 * 2;
  unsigned short* h2b_h = (unsigned short*)cur; cur += (size_t)B * H2 * 2;
  unsigned short* h2b_l = (unsigned short*)cur; cur += (size_t)B * H2 * 2;
  unsigned short* ctxh  = (unsigned short*)cur; cur += (size_t)B * P * 2;
  unsigned short* ctxlo = (unsigned short*)cur; cur += (size_t)B * P * 2;
  float* b1r = (float*)cur;                cur += (size_t)N1 * 4;
  float* b2r = (float*)cur;                cur += (size_t)N2 * 4;
  unsigned short* keys   = (unsigned short*)cur; cur += (size_t)B * S * P * 2;
  unsigned short* values = (unsigned short*)cur; cur += (size_t)B * S * P * 2;
  unsigned short* W1h = (unsigned short*)cur; cur += (size_t)N1 * K1 * 2;
  unsigned short* W1l = (unsigned short*)cur; cur += (size_t)N1 * K1 * 2;
  unsigned short* W2h = (unsigned short*)cur; cur += (size_t)N2 * K2 * 2;
  unsigned short* W2l = (unsigned short*)cur; cur += (size_t)N2 * K2 * 2;

  hipMemsetAsync(d_ws, 0, zero_bytes, stream);

  prep_weights<<<2048, 256, 0, stream>>>(Wih1, Whh1, bih1, bhh1, Wih2, Whh2,
                                         bih2, bhh2, W1h, W1l, W2h, W2l, b1r, b2r);
  kv_gemm<<<dim3((B * S) / 64, 4), 256, 0, stream>>>(enc, Wk, bk, Wv, bv, keys, values);
  ctx0_mean<<<B, P, 0, stream>>>(values, ctxh, ctxlo);

  for (int t = 0; t < T; ++t) {
    const unsigned short* h1ph = (t & 1) ? h1b_h : h1a_h;
    const unsigned short* h1pl = (t & 1) ? h1b_l : h1a_l;
    unsigned short* h1nh = (t & 1) ? h1a_h : h1b_h;
    unsigned short* h1nl = (t & 1) ? h1a_l : h1b_l;
    const unsigned short* h2ph = (t & 1) ? h2b_h : h2a_h;
    const unsigned short* h2pl = (t & 1) ? h2b_l : h2a_l;
    unsigned short* h2nh = (t & 1) ? h2a_h : h2b_h;
    unsigned short* h2nl = (t & 1) ? h2a_l : h2b_l;

    lstm1_mfma<<<dim3(N1 / 16, B / 64), 256, 0, stream>>>(
        W1h, W1l, b1r, emb, y, ctxh, ctxlo, h1ph, h1pl, h1nh, h1nl, c1, t);
    lstm2_mfma<<<dim3(N2 / 16, B / 64), 256, 0, stream>>>(
        W2h, W2l, b2r, h1nh, h1nl, h2ph, h2pl, h2nh, h2nl, c2);
    attn_step<<<B, 256, 0, stream>>>(Wq, bq, emb, b_out, lens, keys, values,
                                     h2nh, h2nl, ctxh, ctxlo, out, t);
  }
}

// Round 4
// 10388.089 us; speedup vs baseline: 3.2775x; 1.4539x over previous
//
#include <hip/hip_runtime.h>
#include <math.h>

#define B 128
#define S 400
#define EENC 512
#define T 300
#define V 30
#define EMB 256
#define H1 512
#define H2 128
#define P 128
#define XD (P + EMB)   // 384
#define K1R (P + H1)   // 640 : LSTM1 serial reduction (ctx + h1); emb precomputed
#define K2 (H1 + H2)   // 640 : LSTM2 reduction
#define N1 (4 * H1)    // 2048
#define N2 (4 * H2)    // 512
#define PRED_SIZE (B * V * T)

typedef __attribute__((ext_vector_type(8))) short short8v;
typedef __attribute__((ext_vector_type(4))) float f32x4;

__device__ __forceinline__ float sigmoidf_(float x) { return 1.0f / (1.0f + expf(-x)); }

__device__ __forceinline__ unsigned short f2bf(float x) {
  unsigned int u = __float_as_uint(x);
  u = (u + 0x7FFFu + ((u >> 16) & 1u)) >> 16;
  return (unsigned short)u;
}
__device__ __forceinline__ float bf2f(unsigned short s) {
  return __uint_as_float(((unsigned int)s) << 16);
}

// ---------------- one-time weight prep ----------------
// W1r[n'][k], n'=4h+s, k = [ctx cols (Wih1 0..128) | Whh1 cols]; split bf16 hi/lo.
// W2r[n'][k], k = [Wih2 cols (h1) | Whh2 cols (h2)].
__global__ void prep_weights(
    const float* __restrict__ Wih1, const float* __restrict__ Whh1,
    const float* __restrict__ bih1, const float* __restrict__ bhh1,
    const float* __restrict__ Wih2, const float* __restrict__ Whh2,
    const float* __restrict__ bih2, const float* __restrict__ bhh2,
    unsigned short* __restrict__ W1h, unsigned short* __restrict__ W1l,
    unsigned short* __restrict__ W2h, unsigned short* __restrict__ W2l,
    float* __restrict__ b1r, float* __restrict__ b2r) {
  const int T1 = N1 * K1R;         // 1,310,720
  const int T2 = N2 * K2;          // 327,680
  const int TOT = T1 + T2 + N1 + N2;
  for (int idx = blockIdx.x * blockDim.x + threadIdx.x; idx < TOT;
       idx += gridDim.x * blockDim.x) {
    if (idx < T1) {
      int np = idx / K1R, k = idx - np * K1R;
      int h = np >> 2, s = np & 3;
      int no = s * H1 + h;
      float v = (k < P) ? Wih1[no * XD + k] : Whh1[no * H1 + (k - P)];
      unsigned short hb = f2bf(v);
      W1h[idx] = hb;
      W1l[idx] = f2bf(v - bf2f(hb));
    } else if (idx < T1 + T2) {
      int i2 = idx - T1;
      int np = i2 / K2, k = i2 - np * K2;
      int h = np >> 2, s = np & 3;
      int no = s * H2 + h;
      float v = (k < H1) ? Wih2[no * H1 + k] : Whh2[no * H2 + (k - H1)];
      unsigned short hb = f2bf(v);
      W2h[i2] = hb;
      W2l[i2] = f2bf(v - bf2f(hb));
    } else if (idx < T1 + T2 + N1) {
      int np = idx - T1 - T2;
      int h = np >> 2, s = np & 3;
      b1r[np] = bih1[s * H1 + h] + bhh1[s * H1 + h];
    } else {
      int np = idx - T1 - T2 - N1;
      int h = np >> 2, s = np & 3;
      b2r[np] = bih2[s * H2 + h] + bhh2[s * H2 + h];
    }
  }
}

// ---------------- EmbW1[v][n'] = emb[v] . Wih1_embcols[n'] (exact f32) ----------------
__global__ __launch_bounds__(256) void emb_w1(
    const float* __restrict__ emb, const float* __restrict__ Wih1,
    float* __restrict__ EmbW1) {
  int idx = blockIdx.x * 256 + threadIdx.x;
  if (idx >= V * N1) return;
  int v = idx >> 11;                // /2048
  int np = idx & (N1 - 1);
  int h = np >> 2, s = np & 3;
  int no = s * H1 + h;
  const float* er = emb + v * EMB;
  const float* wr = Wih1 + no * XD + P;   // emb cols 128..384
  float a = 0.0f;
#pragma unroll 8
  for (int k = 0; k < EMB; k += 4) {
    float4 e4 = *(const float4*)&er[k];
    float4 w4 = *(const float4*)&wr[k];
    a += e4.x * w4.x + e4.y * w4.y + e4.z * w4.z + e4.w * w4.w;
  }
  EmbW1[idx] = a;
}

// ---------------- keys/values precompute GEMM ----------------
// keys[b*S+s][p] bf16 ; valuesT[b][p][s] bf16 (transposed for context pass)
__global__ __launch_bounds__(256) void kv_gemm(
    const float* __restrict__ enc, const float* __restrict__ Wk,
    const float* __restrict__ bk, const float* __restrict__ Wv,
    const float* __restrict__ bv, unsigned short* __restrict__ keys,
    unsigned short* __restrict__ valuesT) {
  __shared__ float As[32][68];
  __shared__ float Ws[32][68];
  const int tid = threadIdx.x;
  const int m0 = blockIdx.x * 64;
  const int n0 = blockIdx.y * 64;
  const int tm = tid & 15, tn = tid >> 4;
  float acc[4][4] = {};
  for (int kc = 0; kc < EENC; kc += 32) {
    for (int i = tid; i < 64 * 32; i += 256) {
      int mm = i >> 5, kk = i & 31;
      As[kk][mm] = enc[(size_t)(m0 + mm) * EENC + kc + kk];
    }
    for (int i = tid; i < 64 * 32; i += 256) {
      int nn = i >> 5, kk = i & 31;
      int n = n0 + nn;
      Ws[kk][nn] = (n < P) ? Wk[n * EENC + kc + kk] : Wv[(n - P) * EENC + kc + kk];
    }
    __syncthreads();
#pragma unroll
    for (int kk = 0; kk < 32; ++kk) {
      float4 av = *(const float4*)&As[kk][tm * 4];
      float4 wv = *(const float4*)&Ws[kk][tn * 4];
      float a[4] = {av.x, av.y, av.z, av.w};
      float w[4] = {wv.x, wv.y, wv.z, wv.w};
#pragma unroll
      for (int ii = 0; ii < 4; ++ii)
#pragma unroll
        for (int jj = 0; jj < 4; ++jj) acc[ii][jj] += a[ii] * w[jj];
    }
    __syncthreads();
  }
#pragma unroll
  for (int ii = 0; ii < 4; ++ii) {
    int m = m0 + tm * 4 + ii;
    int b = m / S, s = m - b * S;
#pragma unroll
    for (int jj = 0; jj < 4; ++jj) {
      int n = n0 + tn * 4 + jj;
      if (n < P) keys[(size_t)m * P + n] = f2bf(acc[ii][jj] + bk[n]);
      else {
        int p = n - P;
        valuesT[((size_t)b * P + p) * S + s] = f2bf(acc[ii][jj] + bv[p]);
      }
    }
  }
}

// ---------------- context0 = mean over S of values ----------------
__global__ void ctx0_mean(const unsigned short* __restrict__ valuesT,
                          unsigned short* __restrict__ ch,
                          unsigned short* __restrict__ cl) {
  int b = blockIdx.x, p = threadIdx.x;
  const uint4* vp = (const uint4*)(valuesT + ((size_t)b * P + p) * S);
  float acc = 0.0f;
#pragma unroll 10
  for (int i = 0; i < S / 8; ++i) {
    uint4 u = vp[i];
    acc += bf2f((unsigned short)(u.x & 0xffff)) + bf2f((unsigned short)(u.x >> 16));
    acc += bf2f((unsigned short)(u.y & 0xffff)) + bf2f((unsigned short)(u.y >> 16));
    acc += bf2f((unsigned short)(u.z & 0xffff)) + bf2f((unsigned short)(u.z >> 16));
    acc += bf2f((unsigned short)(u.w & 0xffff)) + bf2f((unsigned short)(u.w >> 16));
  }
  float m = acc * (1.0f / (float)S);
  unsigned short hb = f2bf(m);
  ch[b * P + p] = hb;
  cl[b * P + p] = f2bf(m - bf2f(hb));
}

// ---------------- LSTM1 step ----------------
// Grid (N1/16=128, B/64=2) x 512 thr = 8 waves = 4 m-waves x 2 k-halves (320 K each).
// acc init = EmbW1[tok][n'] on k-half 0 (emb contribution).
__global__ __launch_bounds__(512) void lstm1_mfma(
    const unsigned short* __restrict__ W1h, const unsigned short* __restrict__ W1l,
    const float* __restrict__ b1r, const float* __restrict__ EmbW1,
    const int* __restrict__ y,
    const unsigned short* __restrict__ ctxh, const unsigned short* __restrict__ ctxlo,
    const unsigned short* __restrict__ h1ph, const unsigned short* __restrict__ h1pl,
    unsigned short* __restrict__ h1nh, unsigned short* __restrict__ h1nl,
    float* __restrict__ c1, int t) {
  __shared__ float Gt[2][64][17];
  __shared__ int tokl[64];
  const int tid = threadIdx.x;
  const int w8 = tid >> 6, l = tid & 63;
  const int lr = l & 15, lq = l >> 4;
  const int mw = w8 & 3, kw = w8 >> 2;
  const int n0 = blockIdx.x * 16;
  const int m0 = blockIdx.y * 64;
  const int brow = m0 + mw * 16 + lr;
  const int nrow = n0 + lr;
  if (tid < 64) tokl[tid] = (t == 0) ? 0 : y[(m0 + tid) * T + t];
  __syncthreads();
  const unsigned short* wph = W1h + (size_t)nrow * K1R;
  const unsigned short* wpl = W1l + (size_t)nrow * K1R;
  f32x4 acc;
  if (kw == 0) {
#pragma unroll
    for (int r = 0; r < 4; ++r)
      acc[r] = EmbW1[tokl[mw * 16 + lq * 4 + r] * N1 + nrow];
  } else {
    acc = (f32x4){0.f, 0.f, 0.f, 0.f};
  }
  if (kw == 0) {
    // 4 ctx chunks (k 0..128) + 6 h1 chunks (h1 offs 0..192)
#pragma unroll
    for (int cc = 0; cc < 4; ++cc) {
      const int ko = cc * 32 + lq * 8;
      short8v ah = *(const short8v*)(ctxh + brow * P + ko);
      short8v al = *(const short8v*)(ctxlo + brow * P + ko);
      short8v bh = *(const short8v*)(wph + ko);
      short8v bl = *(const short8v*)(wpl + ko);
      acc = __builtin_amdgcn_mfma_f32_16x16x32_bf16(ah, bh, acc, 0, 0, 0);
      acc = __builtin_amdgcn_mfma_f32_16x16x32_bf16(ah, bl, acc, 0, 0, 0);
      acc = __builtin_amdgcn_mfma_f32_16x16x32_bf16(al, bh, acc, 0, 0, 0);
    }
#pragma unroll
    for (int cc = 0; cc < 6; ++cc) {
      const int koff = cc * 32 + lq * 8;          // h1 k-offset
      short8v ah = *(const short8v*)(h1ph + brow * H1 + koff);
      short8v al = *(const short8v*)(h1pl + brow * H1 + koff);
      short8v bh = *(const short8v*)(wph + P + koff);
      short8v bl = *(const short8v*)(wpl + P + koff);
      acc = __builtin_amdgcn_mfma_f32_16x16x32_bf16(ah, bh, acc, 0, 0, 0);
      acc = __builtin_amdgcn_mfma_f32_16x16x32_bf16(ah, bl, acc, 0, 0, 0);
      acc = __builtin_amdgcn_mfma_f32_16x16x32_bf16(al, bh, acc, 0, 0, 0);
    }
  } else {
    // 10 h1 chunks (h1 offs 192..512)
#pragma unroll
    for (int cc = 0; cc < 10; ++cc) {
      const int koff = 192 + cc * 32 + lq * 8;
      short8v ah = *(const short8v*)(h1ph + brow * H1 + koff);
      short8v al = *(const short8v*)(h1pl + brow * H1 + koff);
      short8v bh = *(const short8v*)(wph + P + koff);
      short8v bl = *(const short8v*)(wpl + P + koff);
      acc = __builtin_amdgcn_mfma_f32_16x16x32_bf16(ah, bh, acc, 0, 0, 0);
      acc = __builtin_amdgcn_mfma_f32_16x16x32_bf16(ah, bl, acc, 0, 0, 0);
      acc = __builtin_amdgcn_mfma_f32_16x16x32_bf16(al, bh, acc, 0, 0, 0);
    }
  }
#pragma unroll
  for (int r = 0; r < 4; ++r) Gt[kw][mw * 16 + lq * 4 + r][lr] = acc[r];
  __syncthreads();
  // cell update: 256 threads, one (b, h) each
  if (tid < 256) {
    const int bl_ = tid & 63, hl = tid >> 6;     // hl in [0,4)
    const int b = m0 + bl_;
    const int hg = blockIdx.x * 4 + hl;
    const int j = 4 * hl;
    float gi = Gt[0][bl_][j + 0] + Gt[1][bl_][j + 0] + b1r[n0 + j + 0];
    float gf = Gt[0][bl_][j + 1] + Gt[1][bl_][j + 1] + b1r[n0 + j + 1];
    float gg = Gt[0][bl_][j + 2] + Gt[1][bl_][j + 2] + b1r[n0 + j + 2];
    float go = Gt[0][bl_][j + 3] + Gt[1][bl_][j + 3] + b1r[n0 + j + 3];
    float ii = sigmoidf_(gi), ff = sigmoidf_(gf), tg = tanhf(gg), oo = sigmoidf_(go);
    float cn = ff * c1[b * H1 + hg] + ii * tg;
    c1[b * H1 + hg] = cn;
    float hn = oo * tanhf(cn);
    unsigned short hb = f2bf(hn);
    h1nh[b * H1 + hg] = hb;
    h1nl[b * H1 + hg] = f2bf(hn - bf2f(hb));
  }
}

// ---------------- LSTM2 step ----------------
// Grid (N2/16=32, B/16=8) x 256 thr = 4 waves, 4-way K split (160 each).
__global__ __launch_bounds__(256) void lstm2_mfma(
    const unsigned short* __restrict__ W2h, const unsigned short* __restrict__ W2l,
    const float* __restrict__ b2r,
    const unsigned short* __restrict__ h1ch, const unsigned short* __restrict__ h1cl,
    const unsigned short* __restrict__ h2ph, const unsigned short* __restrict__ h2pl,
    unsigned short* __restrict__ h2nh, unsigned short* __restrict__ h2nl,
    float* __restrict__ h2f32, float* __restrict__ c2) {
  __shared__ float Gt[4][16][17];
  const int tid = threadIdx.x;
  const int w = tid >> 6, l = tid & 63;
  const int lr = l & 15, lq = l >> 4;
  const int n0 = blockIdx.x * 16;
  const int m0 = blockIdx.y * 16;
  const int brow = m0 + lr;
  const int nrow = n0 + lr;
  const unsigned short* wph = W2h + (size_t)nrow * K2;
  const unsigned short* wpl = W2l + (size_t)nrow * K2;
  f32x4 acc = {0.f, 0.f, 0.f, 0.f};
  if (w < 3) {
#pragma unroll
    for (int cc = 0; cc < 5; ++cc) {
      const int ko = w * 160 + cc * 32 + lq * 8;  // all < 512 : h1
      short8v ah = *(const short8v*)(h1ch + brow * H1 + ko);
      short8v al = *(const short8v*)(h1cl + brow * H1 + ko);
      short8v bh = *(const short8v*)(wph + ko);
      short8v bl = *(const short8v*)(wpl + ko);
      acc = __builtin_amdgcn_mfma_f32_16x16x32_bf16(ah, bh, acc, 0, 0, 0);
      acc = __builtin_amdgcn_mfma_f32_16x16x32_bf16(ah, bl, acc, 0, 0, 0);
      acc = __builtin_amdgcn_mfma_f32_16x16x32_bf16(al, bh, acc, 0, 0, 0);
    }
  } else {
    {
      const int ko = 480 + lq * 8;                // h1 tail
      short8v ah = *(const short8v*)(h1ch + brow * H1 + ko);
      short8v al = *(const short8v*)(h1cl + brow * H1 + ko);
      short8v bh = *(const short8v*)(wph + ko);
      short8v bl = *(const short8v*)(wpl + ko);
      acc = __builtin_amdgcn_mfma_f32_16x16x32_bf16(ah, bh, acc, 0, 0, 0);
      acc = __builtin_amdgcn_mfma_f32_16x16x32_bf16(ah, bl, acc, 0, 0, 0);
      acc = __builtin_amdgcn_mfma_f32_16x16x32_bf16(al, bh, acc, 0, 0, 0);
    }
#pragma unroll
    for (int cc = 0; cc < 4; ++cc) {
      const int koff = cc * 32 + lq * 8;          // h2 offs 0..128
      short8v ah = *(const short8v*)(h2ph + brow * H2 + koff);
      short8v al = *(const short8v*)(h2pl + brow * H2 + koff);
      short8v bh = *(const short8v*)(wph + H1 + koff);
      short8v bl = *(const short8v*)(wpl + H1 + koff);
      acc = __builtin_amdgcn_mfma_f32_16x16x32_bf16(ah, bh, acc, 0, 0, 0);
      acc = __builtin_amdgcn_mfma_f32_16x16x32_bf16(ah, bl, acc, 0, 0, 0);
      acc = __builtin_amdgcn_mfma_f32_16x16x32_bf16(al, bh, acc, 0, 0, 0);
    }
  }
#pragma unroll
  for (int r = 0; r < 4; ++r) Gt[w][lq * 4 + r][lr] = acc[r];
  __syncthreads();
  // combine 4 K-partials (in-place safe: each loc read only by its writer)
  {
    const int bl_ = tid & 15, j = tid >> 4;
    float s = Gt[0][bl_][j] + Gt[1][bl_][j] + Gt[2][bl_][j] + Gt[3][bl_][j] + b2r[n0 + j];
    __syncthreads();
    Gt[0][bl_][j] = s;
  }
  __syncthreads();
  if (tid < 64) {
    const int bl_ = tid & 15, hl = tid >> 4;
    const int b = m0 + bl_;
    const int hg = blockIdx.x * 4 + hl;
    const int j = 4 * hl;
    float ii = sigmoidf_(Gt[0][bl_][j + 0]);
    float ff = sigmoidf_(Gt[0][bl_][j + 1]);
    float tg = tanhf(Gt[0][bl_][j + 2]);
    float oo = sigmoidf_(Gt[0][bl_][j + 3]);
    float cn = ff * c2[b * H2 + hg] + ii * tg;
    c2[b * H2 + hg] = cn;
    float hn = oo * tanhf(cn);
    unsigned short hb = f2bf(hn);
    h2nh[b * H2 + hg] = hb;
    h2nl[b * H2 + hg] = f2bf(hn - bf2f(hb));
    h2f32[b * H2 + hg] = hn;
  }
}

// ---------------- attention + logits: one block (512 thr) per batch row ----------------
__global__ __launch_bounds__(512) void attn_step(
    const float* __restrict__ Wq, const float* __restrict__ bq,
    const float* __restrict__ emb, const float* __restrict__ b_out,
    const int* __restrict__ lens, const unsigned short* __restrict__ keys,
    const unsigned short* __restrict__ valuesT, const float* __restrict__ h2f32,
    unsigned short* __restrict__ ctxh, unsigned short* __restrict__ ctxlo,
    float* __restrict__ out, int t) {
  __shared__ float h2f[H2];
  __shared__ float qv[P];
  __shared__ float sc[S];
  __shared__ float red[8];
  __shared__ float cpart[4][P];
  __shared__ float ctxf[P];
  const int tid = threadIdx.x;
  const int b = blockIdx.x;
  const int lane = tid & 63, wid = tid >> 6;
  if (tid < H2) h2f[tid] = h2f32[b * H2 + tid];
  __syncthreads();
  // q = h2 @ Wq^T + bq
  if (tid < P) {
    float a = bq[tid];
    const float* wr = &Wq[tid * H2];
#pragma unroll 8
    for (int k = 0; k < H2; k += 4) {
      float4 wv = *(const float4*)&wr[k];
      a += wv.x * h2f[k] + wv.y * h2f[k + 1] + wv.z * h2f[k + 2] + wv.w * h2f[k + 3];
    }
    qv[tid] = a;
  }
  __syncthreads();
  // masked scaled scores: one s per thread
  const float scale = 0.08838834764831845f;
  const int len = lens[b];
  if (tid < S) {
    const uint4* kr = (const uint4*)&keys[((size_t)b * S + tid) * P];
    float a = 0.0f;
#pragma unroll
    for (int k8 = 0; k8 < 16; ++k8) {
      uint4 u = kr[k8];
      const float* q8 = &qv[k8 * 8];
      a += __uint_as_float(u.x << 16) * q8[0] + __uint_as_float(u.x & 0xffff0000u) * q8[1];
      a += __uint_as_float(u.y << 16) * q8[2] + __uint_as_float(u.y & 0xffff0000u) * q8[3];
      a += __uint_as_float(u.z << 16) * q8[4] + __uint_as_float(u.z & 0xffff0000u) * q8[5];
      a += __uint_as_float(u.w << 16) * q8[6] + __uint_as_float(u.w & 0xffff0000u) * q8[7];
    }
    a *= scale;
    if (tid >= len) a = -1e9f;
    sc[tid] = a;
  }
  __syncthreads();
  // softmax: wave shfl reduce + 8-partial LDS combine
  float m_ = (tid < S) ? sc[tid] : -INFINITY;
#pragma unroll
  for (int off = 32; off > 0; off >>= 1) m_ = fmaxf(m_, __shfl_xor(m_, off));
  if (lane == 0) red[wid] = m_;
  __syncthreads();
  float mx = red[0];
#pragma unroll
  for (int i = 1; i < 8; ++i) mx = fmaxf(mx, red[i]);
  __syncthreads();
  float e_ = 0.0f;
  if (tid < S) {
    e_ = expf(sc[tid] - mx);
    sc[tid] = e_;
  }
  float s_ = e_;
#pragma unroll
  for (int off = 32; off > 0; off >>= 1) s_ += __shfl_xor(s_, off);
  if (lane == 0) red[wid] = s_;
  __syncthreads();
  float ssum = red[0] + red[1] + red[2] + red[3] + red[4] + red[5] + red[6] + red[7];
  const float inv = 1.0f / ssum;
  if (tid < S) {
    float wv = sc[tid] * inv;
    sc[tid] = wv;
    if (b == 0) out[PRED_SIZE + (size_t)t * S + tid] = wv;
  }
  __syncthreads();
  // context = w @ values via transposed values: thread (qd, p), 100 s each
  {
    const int qd = tid >> 7, p = tid & 127;
    const uint2* vp = (const uint2*)(valuesT + ((size_t)b * P + p) * S + qd * 100);
    const float* sp = &sc[qd * 100];
    float a = 0.0f;
#pragma unroll
    for (int i = 0; i < 25; ++i) {
      uint2 u = vp[i];
      const float* s4 = &sp[i * 4];
      a += __uint_as_float(u.x << 16) * s4[0] + __uint_as_float(u.x & 0xffff0000u) * s4[1];
      a += __uint_as_float(u.y << 16) * s4[2] + __uint_as_float(u.y & 0xffff0000u) * s4[3];
    }
    cpart[qd][p] = a;
  }
  __syncthreads();
  if (tid < P) {
    float c = cpart[0][tid] + cpart[1][tid] + cpart[2][tid] + cpart[3][tid];
    ctxf[tid] = c;
    unsigned short hb = f2bf(c);
    ctxh[b * P + tid] = hb;
    ctxlo[b * P + tid] = f2bf(c - bf2f(hb));
  }
  __syncthreads();
  // logits: 16 lanes per v (30 v), k split 16x16, shuffle-reduce
  {
    const int g = tid >> 4, l4 = tid & 15;
    if (g < V) {
      float a = 0.0f;
      const float* er = &emb[g * EMB + l4 * 16];
#pragma unroll
      for (int i = 0; i < 4; ++i) {
        float4 e4 = *(const float4*)&er[i * 4];
        int k0 = l4 * 16 + i * 4;
        float x0 = (k0 + 0 < P) ? ctxf[k0 + 0] : h2f[k0 + 0 - P];
        float x1 = (k0 + 1 < P) ? ctxf[k0 + 1] : h2f[k0 + 1 - P];
        float x2 = (k0 + 2 < P) ? ctxf[k0 + 2] : h2f[k0 + 2 - P];
        float x3 = (k0 + 3 < P) ? ctxf[k0 + 3] : h2f[k0 + 3 - P];
        a += e4.x * x0 + e4.y * x1 + e4.z * x2 + e4.w * x3;
      }
      a += __shfl_xor(a, 8);
      a += __shfl_xor(a, 4);
      a += __shfl_xor(a, 2);
      a += __shfl_xor(a, 1);
      if (l4 == 0) out[((size_t)b * V + g) * T + t] = a + b_out[g];
    }
  }
}

extern "C" void kernel_launch(void* const* d_in, const int* in_sizes, int n_in,
                              void* d_out, int out_size, void* d_ws, size_t ws_size,
                              hipStream_t stream) {
  const float* enc  = (const float*)d_in[0];
  const int*   lens = (const int*)d_in[1];
  const int*   y    = (const int*)d_in[2];
  const float* emb  = (const float*)d_in[3];
  const float* Wih1 = (const float*)d_in[4];
  const float* Whh1 = (const float*)d_in[5];
  const float* bih1 = (const float*)d_in[6];
  const float* bhh1 = (const float*)d_in[7];
  const float* Wih2 = (const float*)d_in[8];
  const float* Whh2 = (const float*)d_in[9];
  const float* bih2 = (const float*)d_in[10];
  const float* bhh2 = (const float*)d_in[11];
  const float* Wk   = (const float*)d_in[12];
  const float* bk   = (const float*)d_in[13];
  const float* Wv   = (const float*)d_in[14];
  const float* bv   = (const float*)d_in[15];
  const float* Wq   = (const float*)d_in[16];
  const float* bq   = (const float*)d_in[17];
  const float* b_out= (const float*)d_in[18];
  float* out = (float*)d_out;

  // ---- workspace layout: zeroed region first ----
  char* cur = (char*)d_ws;
  float* c1 = (float*)cur;                      cur += (size_t)B * H1 * 4;
  float* c2 = (float*)cur;                      cur += (size_t)B * H2 * 4;
  unsigned short* h1a_h = (unsigned short*)cur; cur += (size_t)B * H1 * 2;
  unsigned short* h1a_l = (unsigned short*)cur; cur += (size_t)B * H1 * 2;
  unsigned short* h2a_h = (unsigned short*)cur; cur += (size_t)B * H2 * 2;
  unsigned short* h2a_l = (unsigned short*)cur; cur += (size_t)B * H2 * 2;
  const size_t zero_bytes = (size_t)cur - (size_t)d_ws;
  unsigned short* h1b_h = (unsigned short*)cur; cur += (size_t)B * H1 * 2;
  unsigned short* h1b_l = (unsigned short*)cur; cur += (size_t)B * H1 * 2;
  unsigned short* h2b_h = (unsigned short*)cur; cur += (size_t)B * H2 * 2;
  unsigned short* h2b_l = (unsigned short*)cur; cur += (size_t)B * H2 * 2;
  unsigned short* ctxh  = (unsigned short*)cur; cur += (size_t)B * P * 2;
  unsigned short* ctxlo = (unsigned short*)cur; cur += (size_t)B * P * 2;
  float* h2f32 = (float*)cur;                   cur += (size_t)B * H2 * 4;
  float* b1r = (float*)cur;                     cur += (size_t)N1 * 4;
  float* b2r = (float*)cur;                     cur += (size_t)N2 * 4;
  float* EmbW1 = (float*)cur;                   cur += (size_t)V * N1 * 4;
  unsigned short* keys    = (unsigned short*)cur; cur += (size_t)B * S * P * 2;
  unsigned short* valuesT = (unsigned short*)cur; cur += (size_t)B * S * P * 2;
  unsigned short* W1h = (unsigned short*)cur;   cur += (size_t)N1 * K1R * 2;
  unsigned short* W1l = (unsigned short*)cur;   cur += (size_t)N1 * K1R * 2;
  unsigned short* W2h = (unsigned short*)cur;   cur += (size_t)N2 * K2 * 2;
  unsigned short* W2l = (unsigned short*)cur;   cur += (size_t)N2 * K2 * 2;

  hipMemsetAsync(d_ws, 0, zero_bytes, stream);

  prep_weights<<<2048, 256, 0, stream>>>(Wih1, Whh1, bih1, bhh1, Wih2, Whh2,
                                         bih2, bhh2, W1h, W1l, W2h, W2l, b1r, b2r);
  emb_w1<<<(V * N1 + 255) / 256, 256, 0, stream>>>(emb, Wih1, EmbW1);
  kv_gemm<<<dim3((B * S) / 64, 4), 256, 0, stream>>>(enc, Wk, bk, Wv, bv, keys, valuesT);
  ctx0_mean<<<B, P, 0, stream>>>(valuesT, ctxh, ctxlo);

  for (int t = 0; t < T; ++t) {
    const unsigned short* h1ph = (t & 1) ? h1b_h : h1a_h;
    const unsigned short* h1pl = (t & 1) ? h1b_l : h1a_l;
    unsigned short* h1nh = (t & 1) ? h1a_h : h1b_h;
    unsigned short* h1nl = (t & 1) ? h1a_l : h1b_l;
    const unsigned short* h2ph = (t & 1) ? h2b_h : h2a_h;
    const unsigned short* h2pl = (t & 1) ? h2b_l : h2a_l;
    unsigned short* h2nh = (t & 1) ? h2a_h : h2b_h;
    unsigned short* h2nl = (t & 1) ? h2a_l : h2b_l;

    lstm1_mfma<<<dim3(N1 / 16, B / 64), 512, 0, stream>>>(
        W1h, W1l, b1r, EmbW1, y, ctxh, ctxlo, h1ph, h1pl, h1nh, h1nl, c1, t);
    lstm2_mfma<<<dim3(N2 / 16, B / 16), 256, 0, stream>>>(
        W2h, W2l, b2r, h1nh, h1nl, h2ph, h2pl, h2nh, h2nl, h2f32, c2);
    attn_step<<<B, 512, 0, stream>>>(Wq, bq, emb, b_out, lens, keys, valuesT,
                                     h2f32, ctxh, ctxlo, out, t);
  }
}